// Round 3
// baseline (153.490 us; speedup 1.0000x reference)
//
#include <hip/hip_runtime.h>

typedef _Float16 half8 __attribute__((ext_vector_type(8)));
typedef float    f32x16 __attribute__((ext_vector_type(16)));

constexpr int kH = 16;    // heads
constexpr int kO = 1024;  // codebook options
constexpr int kA = 128;   // head size
constexpr int kBS = 4096; // B*S positions
constexpr int MTILE = 64; // positions per block (2 msub x 32)
constexpr int NITER = 16; // option-tiles (32 options) per nhalf

// ---- Pass 1: split W into fp16 hi/lo planes, packed fragment-major ----
// Packed (halfs): (h*32 + t)*8192 + plane*4096 + ks*512 + lane*8 + j
//   where t = o>>5, lane = half*32 + (o&31), ks = a>>4, half = (a>>3)&1, j = a&7
// Each (tile, plane, ks) chunk is 64 lanes x 16 B contiguous.
__global__ void split_w(const float* __restrict__ w, ushort* __restrict__ wp) {
    const int lane = threadIdx.x & 63;
    const int gw   = blockIdx.x * 4 + (threadIdx.x >> 6);
    const int ks   = lane >> 3;          // (2L)>>4
    const int half = (lane >> 2) & 1;    // ((2L)>>3)&1
    const int j    = (2 * lane) & 7;
#pragma unroll
    for (int q = 0; q < 4; ++q) {
        int r = gw * 4 + q;              // global row: h*1024 + o
        int h = r >> 10, o = r & 1023, t = o >> 5, o31 = o & 31;
        float2 v = *(const float2*)(w + r * kA + lane * 2);
        _Float16 h0 = (_Float16)v.x, h1 = (_Float16)v.y;
        _Float16 l0 = (_Float16)(v.x - (float)h0), l1 = (_Float16)(v.y - (float)h1);
        ushort2 hv = { __builtin_bit_cast(ushort, h0), __builtin_bit_cast(ushort, h1) };
        ushort2 lv = { __builtin_bit_cast(ushort, l0), __builtin_bit_cast(ushort, l1) };
        ushort* d = wp + (h * 32 + t) * 8192 + ks * 512 + (half * 32 + o31) * 8 + j;
        *(ushort2*)d = hv;               // plane 0 (hi)
        *(ushort2*)(d + 4096) = lv;      // plane 1 (lo)
    }
}

// ---- Pass 2: occupancy-first. 4-wave blocks, 4 blocks/CU (4 waves/SIMD). ----
// Each wave owns 32 positions x 512 options, one f32x16 accumulator. W streams
// global->reg from L2 (hi double-buffered across iters, lo loaded per iter).
// xl fragments live in wave-private LDS (frees 32 VGPR -> fits 128-VGPR budget
// for 4 waves/SIMD). Zero barriers in the main loop: exposed load latency is
// covered by 3 sibling waves + 3 other blocks on the CU.
__launch_bounds__(256, 4)
__global__ void vq_argmax_gather(const float* __restrict__ x,
                                 const ushort* __restrict__ wp,
                                 const float* __restrict__ cb,
                                 float* __restrict__ out) {
    __shared__ ushort xl_lds[4][8][512];  // [wave][ks][lane*8] = 32 KiB, wave-private
    __shared__ float red_max[2][MTILE];
    __shared__ int   red_idx[2][MTILE];

    const int tid   = threadIdx.x;
    const int lane  = tid & 63;
    const int wv    = tid >> 6;     // 0..3
    const int nhalf = wv >> 1;      // option half (512 each)
    const int msub  = wv & 1;       // 32-position group
    const int bid   = blockIdx.x;
    // XCD-aware: XCD (bid&7) touches only heads {2x,2x+1} -> W+cb L2-resident
    const int h  = ((bid & 7) << 1) | ((bid >> 3) & 1);
    const int p0 = (bid >> 4) * MTILE;

    const int l31  = lane & 31;
    const int half = lane >> 5;

    // this wave's packed-W base: global tile t = nhalf*16 + it
    const ushort* wb = wp + (h * 32 + nhalf * 16) * 8192 + lane * 8;

    // preload tile 0's hi-plane fragments first (latency hides under x-prep)
    half8 A[8];
#pragma unroll
    for (int ks = 0; ks < 8; ++ks)
        A[ks] = *(const half8*)(wb + ks * 512);

    // stationary x: hi fragments in registers, lo fragments in private LDS
    const int mrow = p0 + msub * 32 + l31;
    const float* xb = x + (mrow * kH + h) * kA + half * 8;
    half8 xh[8];
#pragma unroll
    for (int ks = 0; ks < 8; ++ks) {
        float4 v0 = *(const float4*)(xb + ks * 16);
        float4 v1 = *(const float4*)(xb + ks * 16 + 4);
        float va[8] = { v0.x, v0.y, v0.z, v0.w, v1.x, v1.y, v1.z, v1.w };
        half8 hi, lo;
#pragma unroll
        for (int j = 0; j < 8; ++j) {
            _Float16 hj = (_Float16)va[j];
            hi[j] = hj;
            lo[j] = (_Float16)(va[j] - (float)hj);
        }
        xh[ks] = hi;
        *(half8*)&xl_lds[wv][ks][lane * 8] = lo;   // ds_write_b128, own-wave only
    }

    float best = -1e30f;
    int   bidx = 0;
    const int nwb = nhalf * (kO / 2);

    for (int it = 0; it < NITER; ++it) {
        const ushort* tb = wb + it * 8192;
        f32x16 acc = {};
        // pass 1: wh x xh   (accumulation order identical to previous kernels)
#pragma unroll
        for (int ks = 0; ks < 8; ++ks)
            acc = __builtin_amdgcn_mfma_f32_32x32x16_f16(A[ks], xh[ks], acc, 0, 0, 0);
        // pass 2: wh x xl  (xl streamed from private LDS, transient registers)
#pragma unroll
        for (int ks = 0; ks < 8; ++ks) {
            half8 xlk = *(const half8*)&xl_lds[wv][ks][lane * 8];
            acc = __builtin_amdgcn_mfma_f32_32x32x16_f16(A[ks], xlk, acc, 0, 0, 0);
        }
        // pass 3: wl x xh  (lo loads issued here; A is dead -> low reg pressure)
        half8 Bf[8];
#pragma unroll
        for (int ks = 0; ks < 8; ++ks)
            Bf[ks] = *(const half8*)(tb + 4096 + ks * 512);
#pragma unroll
        for (int ks = 0; ks < 8; ++ks)
            acc = __builtin_amdgcn_mfma_f32_32x32x16_f16(Bf[ks], xh[ks], acc, 0, 0, 0);
        // next tile's hi-plane loads (latency covered by fold + sibling waves)
        if (it + 1 < NITER) {
            const ushort* nb = wb + (it + 1) * 8192;
#pragma unroll
            for (int ks = 0; ks < 8; ++ks)
                A[ks] = *(const half8*)(nb + ks * 512);
        }

        // fold 16 option-rows into running scalar argmax (rows ascend with r)
        float lv = acc[0];
        int   lr = 0;
#pragma unroll
        for (int r = 1; r < 16; ++r)
            if (acc[r] > lv) { lv = acc[r]; lr = r; }   // strict >: earliest row wins
        int li = nwb + it * 32 + 4 * half + (lr & 3) + 8 * (lr >> 2);
        if (lv > best) { best = lv; bidx = li; }        // strict >: earlier tile wins
    }

    // merge lane halves (disjoint option rows, same position column)
    {
        float om = __shfl_xor(best, 32, 64);
        int   oi = __shfl_xor(bidx, 32, 64);
        if (om > best || (om == best && oi < bidx)) { best = om; bidx = oi; }
    }
    if (half == 0) {
        red_max[nhalf][msub * 32 + l31] = best;
        red_idx[nhalf][msub * 32 + l31] = bidx;
    }
    __syncthreads();

    // gather: out[p0+row, h, :] = cb[h, argmax, :]
    for (int i = tid; i < MTILE * 32; i += 256) {
        int row = i >> 5, ch = i & 31;
        float m0 = red_max[0][row], m1 = red_max[1][row];
        int o = (m1 > m0) ? red_idx[1][row] : red_idx[0][row]; // ties -> smaller o
        float4 v = *(const float4*)(cb + (h * kO + o) * kA + ch * 4);
        *(float4*)(out + ((p0 + row) * kH + h) * kA + ch * 4) = v;
    }
}

extern "C" void kernel_launch(void* const* d_in, const int* in_sizes, int n_in,
                              void* d_out, int out_size, void* d_ws, size_t ws_size,
                              hipStream_t stream) {
    const float* x  = (const float*)d_in[0];   // [4096,16,128] fp32
    const float* w  = (const float*)d_in[1];   // [16,1024,128] fp32
    const float* cb = (const float*)d_in[2];   // [16,1024,128] fp32
    // d_in[3] = temperature: forward value is temperature-independent
    float* out = (float*)d_out;                // [4096,16,128] fp32

    ushort* wpacked = (ushort*)d_ws;           // 8 MiB packed hi+lo planes

    split_w<<<dim3(1024), dim3(256), 0, stream>>>(w, wpacked);
    vq_argmax_gather<<<dim3((kBS / MTILE) * kH), dim3(256), 0, stream>>>(x, wpacked, cb, out);
}